// Round 27
// baseline (111.579 us; speedup 1.0000x reference)
//
#include <hip/hip_runtime.h>
#include <hip/hip_bf16.h>
#include <stdint.h>

// GPT2Attention: S=2048 E=1024 H=16 d=64 T=4096 past=2048, f32 in/out.
// Round 27: split-K reduced to 2 chunks per q-block (was 3-4): grid 512
// blocks (2/CU exact, all co-resident), chunk bound h0=ceil(NT/2) 128-key
// tiles, chunk 0 never masks. o_part 2 slabs (halved partial traffic),
// merge nc=2 always, 896->512 prologues. Inner attn loop byte-identical to
// r26 (KVBLK=128, 1 barrier/tile, in-register P). Non-attn r26-verbatim.

#define S_LEN 2048
#define E_DIM 1024
#define NHEAD 16
#define HDIM  64
#define T_LEN 4096
#define PASTL 2048

typedef __bf16 bf16x8 __attribute__((ext_vector_type(8)));
typedef __bf16 bf16x4 __attribute__((ext_vector_type(4)));
typedef __bf16 bf16x2 __attribute__((ext_vector_type(2)));
typedef float  f32x4  __attribute__((ext_vector_type(4)));
typedef float  f32x16 __attribute__((ext_vector_type(16)));
typedef unsigned u32x2 __attribute__((ext_vector_type(2)));

static __device__ __forceinline__ f32x4 mfma_bf16(bf16x8 a, bf16x8 b, f32x4 c) {
  return __builtin_amdgcn_mfma_f32_16x16x32_bf16(a, b, c, 0, 0, 0);
}
static __device__ __forceinline__ f32x16 mfma32(bf16x8 a, bf16x8 b, f32x16 c) {
  return __builtin_amdgcn_mfma_f32_32x32x16_bf16(a, b, c, 0, 0, 0);
}

// RNE float -> bf16 bits (values finite)
static __device__ __forceinline__ unsigned int f2bf(float f) {
  union { float f; unsigned int u; } v; v.f = f;
  unsigned int u = v.u;
  return (u + 0x7fffu + ((u >> 16) & 1u)) >> 16;
}

static __device__ __forceinline__ float bf2f(unsigned short u) {
  union { unsigned int u; float f; } v; v.u = (unsigned int)u << 16;
  return v.f;
}

// packed 2xf32 -> dword of 2xbf16 (compiler emits v_cvt_pk_bf16_f32)
static __device__ __forceinline__ unsigned pkbf(float lo, float hi) {
  bf16x2 t = {(__bf16)lo, (__bf16)hi};
  return __builtin_bit_cast(unsigned, t);
}

#define GLOBAL_LOAD_LDS16(gptr, lptr)                                              \
  __builtin_amdgcn_global_load_lds(                                                \
      (const __attribute__((address_space(1))) unsigned int*)(gptr),               \
      (__attribute__((address_space(3))) unsigned int*)(lptr), 16, 0, 0)

// ---------------------------------------------------------------- mega-prep
__global__ __launch_bounds__(256) void prep_kernel(
    const float* __restrict__ past, const float* __restrict__ x,
    const float* __restrict__ W1, const float* __restrict__ W2,
    float* __restrict__ cache, unsigned short* __restrict__ kb,
    unsigned short* __restrict__ xb, unsigned short* __restrict__ w1t,
    unsigned short* __restrict__ w2t, unsigned short* __restrict__ vtb) {
  __shared__ float tile[64][65];
  const int bid = blockIdx.x;
  const int tid = threadIdx.x;
  const int tx = tid & 63, ty = tid >> 6;

  if (bid < 512) {
    const int h = bid >> 5;
    const int t0 = (bid & 31) * 64;
    const float* in = past + (size_t)(NHEAD + h) * T_LEN * HDIM;
    unsigned short* outp = vtb + (size_t)h * HDIM * T_LEN;
#pragma unroll
    for (int r = 0; r < 64; r += 4)
      tile[r + ty][tx] = in[(size_t)(t0 + r + ty) * HDIM + tx];
    __syncthreads();
#pragma unroll
    for (int r = 0; r < 64; r += 4)
      outp[(size_t)(r + ty) * T_LEN + t0 + tx] = f2bf(tile[tx][r + ty]);
  } else if (bid < 1536) {
    const float* in;
    unsigned short* outp;
    int rows, cols, c0, r0;
    if (bid < 1280) {
      int u = bid - 512;
      in = W1; outp = w1t; rows = 1024; cols = 3072;
      c0 = (u % 48) * 64; r0 = (u / 48) * 64;
    } else {
      int u = bid - 1280;
      in = W2; outp = w2t; rows = 1024; cols = 1024;
      c0 = (u & 15) * 64; r0 = (u >> 4) * 64;
    }
#pragma unroll
    for (int r = 0; r < 64; r += 4)
      tile[r + ty][tx] = in[(size_t)(r0 + r + ty) * cols + c0 + tx];
    __syncthreads();
#pragma unroll
    for (int r = 0; r < 64; r += 4)
      outp[(size_t)(c0 + r + ty) * rows + r0 + tx] = f2bf(tile[tx][r + ty]);
  } else {
    const int n4p = (2 * NHEAD * PASTL * HDIM) / 4;  // 1,048,576
    const int n4x = (S_LEN * E_DIM) / 4;             // 524,288
    for (int i = (bid - 1536) * 256 + tid; i < n4p + n4x; i += 2048 * 256) {
      if (i < n4p) {
        int e = i * 4;
        int d = e & 63;
        int t = (e >> 6) & (PASTL - 1);
        int hh = (e >> 17) & (NHEAD - 1);
        int kv = e >> 21;
        size_t full = (((size_t)kv * NHEAD + hh) * T_LEN + t) * HDIM + d;
        float4 v = *(const float4*)(past + full);
        *(float4*)(cache + full) = v;
        if (kv == 0) {
          ushort4 u;
          u.x = f2bf(v.x); u.y = f2bf(v.y); u.z = f2bf(v.z); u.w = f2bf(v.w);
          *(ushort4*)(kb + full) = u;
        }
      } else {
        int j = i - n4p;
        float4 v = ((const float4*)x)[j];
        ushort4 u;
        u.x = f2bf(v.x); u.y = f2bf(v.y); u.z = f2bf(v.z); u.w = f2bf(v.w);
        ((ushort4*)xb)[j] = u;
      }
    }
  }
}

// ---------------------------------------------------------------- GEMM (B^T)
// 64x128 tile, 4 waves, BK=64, acc[2][4], double-buffered K-loop,
// XCD-clustered 1D grid. MODE 0: c_attn epilogue. MODE 1: f32 out.
template <int MODE>
__global__ __launch_bounds__(256) void gemm_bt_kernel(
    const unsigned short* __restrict__ A, const unsigned short* __restrict__ Bt,
    const float* __restrict__ bias, int K,
    float* __restrict__ out_f32, unsigned short* __restrict__ qb,
    float* __restrict__ cache_k, float* __restrict__ cache_v,
    unsigned short* __restrict__ kb, unsigned short* __restrict__ vtb) {
  __shared__ alignas(16) unsigned short As[2][64 * 64];
  __shared__ alignas(16) unsigned short Bs[2][128 * 64];
  const int NPX = (MODE == 0) ? 3 : 1;
  const int bid = blockIdx.x;
  const int xcd = bid & 7;
  const int loc = bid >> 3;
  const int n_idx = xcd * NPX + loc % NPX;
  const int m_idx = loc / NPX;
  const int m0 = m_idx * 64, n0 = n_idx * 128;

  const int tid = threadIdx.x;
  const int lane = tid & 63;
  const int w = tid >> 6;
  const int wm = w >> 1, wn = w & 1;
  const int lr = lane & 15;
  const int lg = lane >> 4;

  f32x4 acc[2][4];
#pragma unroll
  for (int i = 0; i < 2; ++i)
#pragma unroll
    for (int j = 0; j < 4; ++j) acc[i][j] = f32x4{0.f, 0.f, 0.f, 0.f};

  const int srow = tid >> 3;
  const int sseg = (tid & 7) ^ (srow & 7);
  const unsigned short* ga0 = A + (size_t)(m0 + srow) * K + sseg * 8;
  const unsigned short* gb0 = Bt + (size_t)(n0 + srow) * K + sseg * 8;

  auto stage = [&](int b, int k0) {
    GLOBAL_LOAD_LDS16(ga0 + k0, (char*)As[b] + tid * 16);
    GLOBAL_LOAD_LDS16(ga0 + (size_t)32 * K + k0, (char*)As[b] + 4096 + tid * 16);
#pragma unroll
    for (int j = 0; j < 4; ++j)
      GLOBAL_LOAD_LDS16(gb0 + (size_t)(32 * j) * K + k0,
                        (char*)Bs[b] + j * 4096 + tid * 16);
  };

  const int NKS = K >> 6;  // 16
  stage(0, 0);
  int cur = 0;
  for (int i = 0; i < NKS; ++i) {
    asm volatile("s_waitcnt vmcnt(0)" ::: "memory");
    __builtin_amdgcn_s_barrier();
    __builtin_amdgcn_sched_barrier(0);
    if (i + 1 < NKS) stage(cur ^ 1, (i + 1) * 64);  // flies under compute

#pragma unroll
    for (int kk = 0; kk < 2; ++kk) {
      bf16x8 af[2], bfr[4];
#pragma unroll
      for (int mi = 0; mi < 2; ++mi) {
        int row = wm * 32 + mi * 16 + lr;
        int slot = (kk * 4 + lg) ^ (row & 7);
        af[mi] = *reinterpret_cast<const bf16x8*>((const char*)As[cur] + row * 128 + slot * 16);
      }
#pragma unroll
      for (int ni = 0; ni < 4; ++ni) {
        int row = wn * 64 + ni * 16 + lr;
        int slot = (kk * 4 + lg) ^ (row & 7);
        bfr[ni] = *reinterpret_cast<const bf16x8*>((const char*)Bs[cur] + row * 128 + slot * 16);
      }
#pragma unroll
      for (int mi = 0; mi < 2; ++mi)
#pragma unroll
        for (int ni = 0; ni < 4; ++ni)
          acc[mi][ni] = mfma_bf16(af[mi], bfr[ni], acc[mi][ni]);
    }
    cur ^= 1;
  }

#pragma unroll
  for (int ni = 0; ni < 4; ++ni) {
    int n = n0 + wn * 64 + ni * 16 + lr;
    float bv = bias[n];
#pragma unroll
    for (int mi = 0; mi < 2; ++mi) {
      int mbase = m0 + wm * 32 + mi * 16 + lg * 4;
      float v4[4];
#pragma unroll
      for (int r = 0; r < 4; ++r) v4[r] = acc[mi][ni][r] + bv;
      if (MODE == 0) {
        if (n < E_DIM) {
#pragma unroll
          for (int r = 0; r < 4; ++r)
            qb[(size_t)(mbase + r) * E_DIM + n] = f2bf(v4[r] * 0.18033688f);
        } else if (n < 2 * E_DIM) {
          int e = n - E_DIM;
          size_t base = ((size_t)(e >> 6) * T_LEN + (PASTL + mbase)) * HDIM + (e & 63);
#pragma unroll
          for (int r = 0; r < 4; ++r) {
            cache_k[base + (size_t)r * HDIM] = v4[r];
            kb[base + (size_t)r * HDIM] = f2bf(v4[r]);
          }
        } else {
          int e = n - 2 * E_DIM;
          int hh = e >> 6, d = e & 63;
          size_t base = ((size_t)hh * T_LEN + (PASTL + mbase)) * HDIM + d;
#pragma unroll
          for (int r = 0; r < 4; ++r) cache_v[base + (size_t)r * HDIM] = v4[r];
          ushort4 u;
          u.x = f2bf(v4[0]); u.y = f2bf(v4[1]);
          u.z = f2bf(v4[2]); u.w = f2bf(v4[3]);
          *(ushort4*)(vtb + ((size_t)hh * HDIM + d) * T_LEN + PASTL + mbase) = u;
        }
      } else {
#pragma unroll
        for (int r = 0; r < 4; ++r)
          out_f32[(size_t)(mbase + r) * E_DIM + n] = v4[r];
      }
    }
  }
}

// ---------------------------------------------------------------- attention
// KVBLK=128, ONE barrier/tile (r26 inner loop verbatim). Split-K = 2 chunks:
// grid 512 blocks (2/CU exact). h=(fid&7)+(fid>=256?8:0); g=(fid>>3)-(fid>=
// 256?32:0) in 0..31; x=g>>1 (q-block), c=g&1 (chunk). NT2full=17+x tiles;
// h0=(18+x)>>1; chunk0=[0,h0) (never masks), chunk1=[h0,NT2full).
// o_part[c][h][row][d] bf16 c in {0,1}; l_part[c][h][row] f32.
__global__ __launch_bounds__(256) void attn_kernel(
    const unsigned short* __restrict__ qb, const unsigned short* __restrict__ kb,
    const unsigned short* __restrict__ vt,
    unsigned short* __restrict__ o_part, float* __restrict__ l_part) {
  __shared__ alignas(16) unsigned short Ks[2][128 * 64];
  __shared__ alignas(16) unsigned short Vs[2][64 * 128];
  const int fid = blockIdx.x;  // 0..511
  const int h = (fid & 7) + ((fid >= 256) ? 8 : 0);
  const int g = (fid >> 3) - ((fid >= 256) ? 32 : 0);  // 0..31
  const int x = g >> 1;
  const int c = g & 1;

  const int tid = threadIdx.x;
  const int w = tid >> 6;
  const int lane = tid & 63;
  const int l31 = lane & 31;
  const int hi = lane >> 5;
  const int hi4 = hi * 4;
  const int q0 = x * 128 + w * 32;

  // Q B-frags: lane (col=q=l31, hi) holds d = kk*16 + hi*8 + 0..7
  const unsigned short* qrow = qb + (size_t)(q0 + l31) * E_DIM + h * HDIM + hi * 8;
  bf16x8 qf[4];
#pragma unroll
  for (int kk = 0; kk < 4; ++kk)
    qf[kk] = *reinterpret_cast<const bf16x8*>(qrow + kk * 16);

  const unsigned short* kh = kb + (size_t)h * T_LEN * HDIM;
  const unsigned short* vh = vt + (size_t)h * HDIM * T_LEN;

  // K staging: round j (0..3): rows t0+32j+(tid>>3), seg (tid&7)^(row&7).
  const int srow = tid >> 3;  // 0..31
  const int sseg = (tid & 7) ^ (srow & 7);
  const unsigned short* ksrc = kh + (size_t)srow * HDIM + sseg * 8;
  // V staging: round j (0..3): d = 16j+(tid>>4), seg (tid&15)^(d&7).
  const int vrow = tid >> 4;  // 0..15
  const int vseg = (tid & 15) ^ (vrow & 7);
  const unsigned short* vsrc = vh + (size_t)vrow * T_LEN + vseg * 8;

  f32x16 o0, o1, zc;
#pragma unroll
  for (int i = 0; i < 16; ++i) { o0[i] = 0.f; o1[i] = 0.f; zc[i] = 0.f; }
  float lsum = 0.f;

  const int NT2full = 17 + x;            // 128-key tiles for this q-block
  const int h0 = (18 + x) >> 1;          // chunk boundary (9..16)
  const int tb = c ? h0 : 0;
  const int te = c ? NT2full : h0;
  const int NT = te - tb;                // 8..16
  const int tbeg = tb * 128;
  const int qpp = q0 + l31 + PASTL;      // key > qpp => masked

  auto stageK = [&](int b, int t0) {
#pragma unroll
    for (int j = 0; j < 4; ++j)
      GLOBAL_LOAD_LDS16(ksrc + (size_t)(t0 + 32 * j) * HDIM,
                        (char*)Ks[b] + j * 4096 + tid * 16);
  };
  auto stageV = [&](int b, int t0) {
#pragma unroll
    for (int j = 0; j < 4; ++j)
      GLOBAL_LOAD_LDS16(vsrc + (size_t)(16 * j) * T_LEN + t0,
                        (char*)Vs[b] + j * 4096 + tid * 16);
  };

  stageK(0, tbeg);
  stageV(0, tbeg);
  int cur = 0;
  int t0 = tbeg;
  for (int i = 0; i < NT; ++i, t0 += 128) {
    const bool more = (i + 1 < NT);
    // ---- single sync point: K(i)+V(i) landed; buf^1 free (barrier) ----
    asm volatile("s_waitcnt vmcnt(0)" ::: "memory");
    __builtin_amdgcn_s_barrier();
    __builtin_amdgcn_sched_barrier(0);
    if (more) {
      stageK(cur ^ 1, t0 + 128);
      stageV(cur ^ 1, t0 + 128);
    }

    // ---- QK^T + softmax + P-relayout, two rb-pairs (keys 0-63, 64-127) ----
    const bool partial = (t0 + 127 > q0 + PASTL);  // wave-uniform
    const int thr = qpp - t0;
    union U4 { unsigned u[4]; bf16x8 v; };
    U4 pa[8];
#pragma unroll
    for (int half = 0; half < 2; ++half) {
      const int rbA = half * 2, rbB = half * 2 + 1;
      f32x16 sA, sB;
      __builtin_amdgcn_s_setprio(1);
      {
        int rA = rbA * 32 + l31, rB = rbB * 32 + l31;
        int slA = hi ^ (rA & 7), slB = hi ^ (rB & 7);
        bf16x8 kA = *reinterpret_cast<const bf16x8*>((const char*)Ks[cur] + rA * 128 + slA * 16);
        bf16x8 kB = *reinterpret_cast<const bf16x8*>((const char*)Ks[cur] + rB * 128 + slB * 16);
        sA = mfma32(kA, qf[0], zc);
        sB = mfma32(kB, qf[0], zc);
      }
#pragma unroll
      for (int kk = 1; kk < 4; ++kk) {
        int rA = rbA * 32 + l31, rB = rbB * 32 + l31;
        int slA = (kk * 2 + hi) ^ (rA & 7), slB = (kk * 2 + hi) ^ (rB & 7);
        bf16x8 kA = *reinterpret_cast<const bf16x8*>((const char*)Ks[cur] + rA * 128 + slA * 16);
        bf16x8 kB = *reinterpret_cast<const bf16x8*>((const char*)Ks[cur] + rB * 128 + slB * 16);
        sA = mfma32(kA, qf[kk], sA);
        sB = mfma32(kB, qf[kk], sB);
      }
      __builtin_amdgcn_s_setprio(0);

      unsigned aw[8], bw[8];
      if (!partial) {
#pragma unroll
        for (int i2 = 0; i2 < 8; ++i2) {
          float p0 = __builtin_amdgcn_exp2f(sA[2 * i2]);
          float p1 = __builtin_amdgcn_exp2f(sA[2 * i2 + 1]);
          float p2 = __builtin_amdgcn_exp2f(sB[2 * i2]);
          float p3 = __builtin_amdgcn_exp2f(sB[2 * i2 + 1]);
          lsum += (p0 + p1) + (p2 + p3);
          aw[i2] = pkbf(p0, p1);
          bw[i2] = pkbf(p2, p3);
        }
      } else {
        const int bo = half * 64;
#pragma unroll
        for (int i2 = 0; i2 < 8; ++i2) {
          int r0 = 2 * i2;
          int ko = (r0 & 3) + 8 * (r0 >> 2) + hi4 + bo;
          float p0 = __builtin_amdgcn_exp2f(sA[r0]);
          float p1 = __builtin_amdgcn_exp2f(sA[r0 + 1]);
          float p2 = __builtin_amdgcn_exp2f(sB[r0]);
          float p3 = __builtin_amdgcn_exp2f(sB[r0 + 1]);
          if (ko > thr) p0 = 0.f;
          if (ko + 1 > thr) p1 = 0.f;
          if (ko + 32 > thr) p2 = 0.f;
          if (ko + 33 > thr) p3 = 0.f;
          lsum += (p0 + p1) + (p2 + p3);
          aw[i2] = pkbf(p0, p1);
          bw[i2] = pkbf(p2, p3);
        }
      }

      {
        u32x2 r02 = __builtin_amdgcn_permlane32_swap(aw[0], aw[2], false, false);
        u32x2 r13 = __builtin_amdgcn_permlane32_swap(aw[1], aw[3], false, false);
        pa[4 * half + 0].u[0] = r02[0]; pa[4 * half + 0].u[1] = r13[0];
        pa[4 * half + 0].u[2] = r02[1]; pa[4 * half + 0].u[3] = r13[1];
        u32x2 r46 = __builtin_amdgcn_permlane32_swap(aw[4], aw[6], false, false);
        u32x2 r57 = __builtin_amdgcn_permlane32_swap(aw[5], aw[7], false, false);
        pa[4 * half + 1].u[0] = r46[0]; pa[4 * half + 1].u[1] = r57[0];
        pa[4 * half + 1].u[2] = r46[1]; pa[4 * half + 1].u[3] = r57[1];
        u32x2 s02 = __builtin_amdgcn_permlane32_swap(bw[0], bw[2], false, false);
        u32x2 s13 = __builtin_amdgcn_permlane32_swap(bw[1], bw[3], false, false);
        pa[4 * half + 2].u[0] = s02[0]; pa[4 * half + 2].u[1] = s13[0];
        pa[4 * half + 2].u[2] = s02[1]; pa[4 * half + 2].u[3] = s13[1];
        u32x2 s46 = __builtin_amdgcn_permlane32_swap(bw[4], bw[6], false, false);
        u32x2 s57 = __builtin_amdgcn_permlane32_swap(bw[5], bw[7], false, false);
        pa[4 * half + 3].u[0] = s46[0]; pa[4 * half + 3].u[1] = s57[0];
        pa[4 * half + 3].u[2] = s46[1]; pa[4 * half + 3].u[3] = s57[1];
      }
    }

    // ---- PV: 8 k-slices; V rows 256B, slot = (2ks+hi)^(d&7) ----
    __builtin_amdgcn_s_setprio(1);
#pragma unroll
    for (int ks = 0; ks < 8; ++ks) {
      int d0 = l31, d1 = 32 + l31;
      int sl0 = (2 * ks + hi) ^ (d0 & 7);
      int sl1 = (2 * ks + hi) ^ (d1 & 7);
      bf16x8 v0 = *reinterpret_cast<const bf16x8*>((const char*)Vs[cur] + d0 * 256 + sl0 * 16);
      bf16x8 v1 = *reinterpret_cast<const bf16x8*>((const char*)Vs[cur] + d1 * 256 + sl1 * 16);
      o0 = mfma32(pa[ks].v, v0, o0);
      o1 = mfma32(pa[ks].v, v1, o1);
    }
    __builtin_amdgcn_s_setprio(0);
    cur ^= 1;
  }

  lsum += __shfl_xor(lsum, 32);

  // partials: o_part[c][h][row][d] bf16 (c in {0,1}), l_part[c][h][row] f32
  unsigned short* op = o_part + ((size_t)(c * NHEAD + h) * S_LEN) * HDIM;
  float* lp = l_part + (size_t)(c * NHEAD + h) * S_LEN;
  if (hi == 0) lp[q0 + l31] = lsum;
#pragma unroll
  for (int r = 0; r < 16; ++r) {
    int qr = (r & 3) + 8 * (r >> 2) + hi4;
    op[(size_t)(q0 + qr) * HDIM + l31] = f2bf(o0[r]);
    op[(size_t)(q0 + qr) * HDIM + 32 + l31] = f2bf(o1[r]);
  }
}

// Merge the 2 chunk partials and normalize -> ab bf16.
__global__ __launch_bounds__(256) void attn_merge_kernel(
    const unsigned short* __restrict__ o_part, const float* __restrict__ l_part,
    unsigned short* __restrict__ ab) {
  const int flat = blockIdx.x * 256 + threadIdx.x;
  const int d4 = flat & 15;
  const int row = (flat >> 4) & (S_LEN - 1);
  const int h = flat >> 15;
  const size_t cstride_o = (size_t)NHEAD * S_LEN * HDIM;
  const size_t base_o = (((size_t)h * S_LEN) + row) * HDIM + d4 * 4;
  ushort4 u0 = *(const ushort4*)(o_part + base_o);
  ushort4 u1 = *(const ushort4*)(o_part + cstride_o + base_o);
  float l = l_part[(size_t)h * S_LEN + row] +
            l_part[(size_t)NHEAD * S_LEN + (size_t)h * S_LEN + row];
  float inv = 1.f / l;
  ushort4 u;
  u.x = f2bf((bf2f(u0.x) + bf2f(u1.x)) * inv);
  u.y = f2bf((bf2f(u0.y) + bf2f(u1.y)) * inv);
  u.z = f2bf((bf2f(u0.z) + bf2f(u1.z)) * inv);
  u.w = f2bf((bf2f(u0.w) + bf2f(u1.w)) * inv);
  *(ushort4*)(ab + (size_t)row * E_DIM + h * HDIM + d4 * 4) = u;
}

// ---------------------------------------------------------------- launch

extern "C" void kernel_launch(void* const* d_in, const int* in_sizes, int n_in,
                              void* d_out, int out_size, void* d_ws, size_t ws_size,
                              hipStream_t stream) {
  (void)in_sizes; (void)n_in; (void)out_size; (void)ws_size;
  const float* x    = (const float*)d_in[0];
  const float* past = (const float*)d_in[1];
  const float* W1   = (const float*)d_in[2];
  const float* b1   = (const float*)d_in[3];
  const float* W2   = (const float*)d_in[4];
  const float* b2   = (const float*)d_in[5];

  float* out = (float*)d_out;
  float* cache_k = out + (size_t)S_LEN * E_DIM;
  float* cache_v = cache_k + (size_t)NHEAD * T_LEN * HDIM;

  // Workspace layout (42.5 MiB peak), lifetime-disjoint overlaps:
  //   [0,2)   w2t ; [2,6) qb ; [6,14) kb ; [14,22) vtb
  //   [22,26) xb -> ab ; [26,32) w1t -> o_part ; [26,42) o_part (2 slabs used)
  //   [42,42.5) l_part
  char* ws = (char*)d_ws;
  unsigned short* w2t = (unsigned short*)(ws);
  unsigned short* qb  = (unsigned short*)(ws + (size_t)(2u  << 20));
  unsigned short* kb  = (unsigned short*)(ws + (size_t)(6u  << 20));
  unsigned short* vtb = (unsigned short*)(ws + (size_t)(14u << 20));
  unsigned short* xb  = (unsigned short*)(ws + (size_t)(22u << 20));
  unsigned short* ab  = (unsigned short*)(ws + (size_t)(22u << 20));  // reuse xb
  unsigned short* w1t = (unsigned short*)(ws + (size_t)(26u << 20));
  unsigned short* o_part = (unsigned short*)(ws + (size_t)(26u << 20));  // reuse w1t
  float* l_part = (float*)(ws + (size_t)(42u << 20));

  prep_kernel<<<3584, 256, 0, stream>>>(past, x, W1, W2, cache_k, kb, xb, w1t,
                                        w2t, vtb);
  gemm_bt_kernel<0><<<768, 256, 0, stream>>>(
      xb, w1t, b1, 1024, nullptr, qb, cache_k, cache_v, kb, vtb);
  attn_kernel<<<dim3(512), 256, 0, stream>>>(qb, kb, vtb, o_part, l_part);
  attn_merge_kernel<<<(NHEAD * S_LEN * 16) / 256, 256, 0, stream>>>(o_part, l_part, ab);
  gemm_bt_kernel<1><<<256, 256, 0, stream>>>(
      ab, w2t, b2, 1024, out, nullptr, nullptr, nullptr, nullptr, nullptr);
}

// Round 28
// 110.708 us; speedup vs baseline: 1.0079x; 1.0079x over previous
//
#include <hip/hip_runtime.h>
#include <hip/hip_bf16.h>
#include <stdint.h>

// GPT2Attention: S=2048 E=1024 H=16 d=64 T=4096 past=2048, f32 in/out.
// FINAL (= r26, verified 110.8us): mega-prep (1 launch) -> dbuf XCD-clustered
// 64x128 GEMM<0> -> attn (KVBLK=128, ONE barrier/tile, 32x32 swapped-QK,
// in-register P via permlane32_swap, 896 blocks, fid%8==head%8 affinity)
// -> merge -> dbuf GEMM<1>. r27's 2-chunk split-K regressed (coarser blocks'
// longer critical path outweighed halved partial traffic) -> reverted.

#define S_LEN 2048
#define E_DIM 1024
#define NHEAD 16
#define HDIM  64
#define T_LEN 4096
#define PASTL 2048

typedef __bf16 bf16x8 __attribute__((ext_vector_type(8)));
typedef __bf16 bf16x4 __attribute__((ext_vector_type(4)));
typedef __bf16 bf16x2 __attribute__((ext_vector_type(2)));
typedef float  f32x4  __attribute__((ext_vector_type(4)));
typedef float  f32x16 __attribute__((ext_vector_type(16)));
typedef unsigned u32x2 __attribute__((ext_vector_type(2)));

static __device__ __forceinline__ f32x4 mfma_bf16(bf16x8 a, bf16x8 b, f32x4 c) {
  return __builtin_amdgcn_mfma_f32_16x16x32_bf16(a, b, c, 0, 0, 0);
}
static __device__ __forceinline__ f32x16 mfma32(bf16x8 a, bf16x8 b, f32x16 c) {
  return __builtin_amdgcn_mfma_f32_32x32x16_bf16(a, b, c, 0, 0, 0);
}

// RNE float -> bf16 bits (values finite)
static __device__ __forceinline__ unsigned int f2bf(float f) {
  union { float f; unsigned int u; } v; v.f = f;
  unsigned int u = v.u;
  return (u + 0x7fffu + ((u >> 16) & 1u)) >> 16;
}

static __device__ __forceinline__ float bf2f(unsigned short u) {
  union { unsigned int u; float f; } v; v.u = (unsigned int)u << 16;
  return v.f;
}

// packed 2xf32 -> dword of 2xbf16 (compiler emits v_cvt_pk_bf16_f32)
static __device__ __forceinline__ unsigned pkbf(float lo, float hi) {
  bf16x2 t = {(__bf16)lo, (__bf16)hi};
  return __builtin_bit_cast(unsigned, t);
}

#define GLOBAL_LOAD_LDS16(gptr, lptr)                                              \
  __builtin_amdgcn_global_load_lds(                                                \
      (const __attribute__((address_space(1))) unsigned int*)(gptr),               \
      (__attribute__((address_space(3))) unsigned int*)(lptr), 16, 0, 0)

// ---------------------------------------------------------------- mega-prep
__global__ __launch_bounds__(256) void prep_kernel(
    const float* __restrict__ past, const float* __restrict__ x,
    const float* __restrict__ W1, const float* __restrict__ W2,
    float* __restrict__ cache, unsigned short* __restrict__ kb,
    unsigned short* __restrict__ xb, unsigned short* __restrict__ w1t,
    unsigned short* __restrict__ w2t, unsigned short* __restrict__ vtb) {
  __shared__ float tile[64][65];
  const int bid = blockIdx.x;
  const int tid = threadIdx.x;
  const int tx = tid & 63, ty = tid >> 6;

  if (bid < 512) {
    const int h = bid >> 5;
    const int t0 = (bid & 31) * 64;
    const float* in = past + (size_t)(NHEAD + h) * T_LEN * HDIM;
    unsigned short* outp = vtb + (size_t)h * HDIM * T_LEN;
#pragma unroll
    for (int r = 0; r < 64; r += 4)
      tile[r + ty][tx] = in[(size_t)(t0 + r + ty) * HDIM + tx];
    __syncthreads();
#pragma unroll
    for (int r = 0; r < 64; r += 4)
      outp[(size_t)(r + ty) * T_LEN + t0 + tx] = f2bf(tile[tx][r + ty]);
  } else if (bid < 1536) {
    const float* in;
    unsigned short* outp;
    int rows, cols, c0, r0;
    if (bid < 1280) {
      int u = bid - 512;
      in = W1; outp = w1t; rows = 1024; cols = 3072;
      c0 = (u % 48) * 64; r0 = (u / 48) * 64;
    } else {
      int u = bid - 1280;
      in = W2; outp = w2t; rows = 1024; cols = 1024;
      c0 = (u & 15) * 64; r0 = (u >> 4) * 64;
    }
#pragma unroll
    for (int r = 0; r < 64; r += 4)
      tile[r + ty][tx] = in[(size_t)(r0 + r + ty) * cols + c0 + tx];
    __syncthreads();
#pragma unroll
    for (int r = 0; r < 64; r += 4)
      outp[(size_t)(c0 + r + ty) * rows + r0 + tx] = f2bf(tile[tx][r + ty]);
  } else {
    const int n4p = (2 * NHEAD * PASTL * HDIM) / 4;  // 1,048,576
    const int n4x = (S_LEN * E_DIM) / 4;             // 524,288
    for (int i = (bid - 1536) * 256 + tid; i < n4p + n4x; i += 2048 * 256) {
      if (i < n4p) {
        int e = i * 4;
        int d = e & 63;
        int t = (e >> 6) & (PASTL - 1);
        int hh = (e >> 17) & (NHEAD - 1);
        int kv = e >> 21;
        size_t full = (((size_t)kv * NHEAD + hh) * T_LEN + t) * HDIM + d;
        float4 v = *(const float4*)(past + full);
        *(float4*)(cache + full) = v;
        if (kv == 0) {
          ushort4 u;
          u.x = f2bf(v.x); u.y = f2bf(v.y); u.z = f2bf(v.z); u.w = f2bf(v.w);
          *(ushort4*)(kb + full) = u;
        }
      } else {
        int j = i - n4p;
        float4 v = ((const float4*)x)[j];
        ushort4 u;
        u.x = f2bf(v.x); u.y = f2bf(v.y); u.z = f2bf(v.z); u.w = f2bf(v.w);
        ((ushort4*)xb)[j] = u;
      }
    }
  }
}

// ---------------------------------------------------------------- GEMM (B^T)
// 64x128 tile, 4 waves, BK=64, acc[2][4], double-buffered K-loop,
// XCD-clustered 1D grid. MODE 0: c_attn epilogue. MODE 1: f32 out.
template <int MODE>
__global__ __launch_bounds__(256) void gemm_bt_kernel(
    const unsigned short* __restrict__ A, const unsigned short* __restrict__ Bt,
    const float* __restrict__ bias, int K,
    float* __restrict__ out_f32, unsigned short* __restrict__ qb,
    float* __restrict__ cache_k, float* __restrict__ cache_v,
    unsigned short* __restrict__ kb, unsigned short* __restrict__ vtb) {
  __shared__ alignas(16) unsigned short As[2][64 * 64];
  __shared__ alignas(16) unsigned short Bs[2][128 * 64];
  const int NPX = (MODE == 0) ? 3 : 1;
  const int bid = blockIdx.x;
  const int xcd = bid & 7;
  const int loc = bid >> 3;
  const int n_idx = xcd * NPX + loc % NPX;
  const int m_idx = loc / NPX;
  const int m0 = m_idx * 64, n0 = n_idx * 128;

  const int tid = threadIdx.x;
  const int lane = tid & 63;
  const int w = tid >> 6;
  const int wm = w >> 1, wn = w & 1;
  const int lr = lane & 15;
  const int lg = lane >> 4;

  f32x4 acc[2][4];
#pragma unroll
  for (int i = 0; i < 2; ++i)
#pragma unroll
    for (int j = 0; j < 4; ++j) acc[i][j] = f32x4{0.f, 0.f, 0.f, 0.f};

  const int srow = tid >> 3;
  const int sseg = (tid & 7) ^ (srow & 7);
  const unsigned short* ga0 = A + (size_t)(m0 + srow) * K + sseg * 8;
  const unsigned short* gb0 = Bt + (size_t)(n0 + srow) * K + sseg * 8;

  auto stage = [&](int b, int k0) {
    GLOBAL_LOAD_LDS16(ga0 + k0, (char*)As[b] + tid * 16);
    GLOBAL_LOAD_LDS16(ga0 + (size_t)32 * K + k0, (char*)As[b] + 4096 + tid * 16);
#pragma unroll
    for (int j = 0; j < 4; ++j)
      GLOBAL_LOAD_LDS16(gb0 + (size_t)(32 * j) * K + k0,
                        (char*)Bs[b] + j * 4096 + tid * 16);
  };

  const int NKS = K >> 6;  // 16
  stage(0, 0);
  int cur = 0;
  for (int i = 0; i < NKS; ++i) {
    asm volatile("s_waitcnt vmcnt(0)" ::: "memory");
    __builtin_amdgcn_s_barrier();
    __builtin_amdgcn_sched_barrier(0);
    if (i + 1 < NKS) stage(cur ^ 1, (i + 1) * 64);  // flies under compute

#pragma unroll
    for (int kk = 0; kk < 2; ++kk) {
      bf16x8 af[2], bfr[4];
#pragma unroll
      for (int mi = 0; mi < 2; ++mi) {
        int row = wm * 32 + mi * 16 + lr;
        int slot = (kk * 4 + lg) ^ (row & 7);
        af[mi] = *reinterpret_cast<const bf16x8*>((const char*)As[cur] + row * 128 + slot * 16);
      }
#pragma unroll
      for (int ni = 0; ni < 4; ++ni) {
        int row = wn * 64 + ni * 16 + lr;
        int slot = (kk * 4 + lg) ^ (row & 7);
        bfr[ni] = *reinterpret_cast<const bf16x8*>((const char*)Bs[cur] + row * 128 + slot * 16);
      }
#pragma unroll
      for (int mi = 0; mi < 2; ++mi)
#pragma unroll
        for (int ni = 0; ni < 4; ++ni)
          acc[mi][ni] = mfma_bf16(af[mi], bfr[ni], acc[mi][ni]);
    }
    cur ^= 1;
  }

#pragma unroll
  for (int ni = 0; ni < 4; ++ni) {
    int n = n0 + wn * 64 + ni * 16 + lr;
    float bv = bias[n];
#pragma unroll
    for (int mi = 0; mi < 2; ++mi) {
      int mbase = m0 + wm * 32 + mi * 16 + lg * 4;
      float v4[4];
#pragma unroll
      for (int r = 0; r < 4; ++r) v4[r] = acc[mi][ni][r] + bv;
      if (MODE == 0) {
        if (n < E_DIM) {
#pragma unroll
          for (int r = 0; r < 4; ++r)
            qb[(size_t)(mbase + r) * E_DIM + n] = f2bf(v4[r] * 0.18033688f);
        } else if (n < 2 * E_DIM) {
          int e = n - E_DIM;
          size_t base = ((size_t)(e >> 6) * T_LEN + (PASTL + mbase)) * HDIM + (e & 63);
#pragma unroll
          for (int r = 0; r < 4; ++r) {
            cache_k[base + (size_t)r * HDIM] = v4[r];
            kb[base + (size_t)r * HDIM] = f2bf(v4[r]);
          }
        } else {
          int e = n - 2 * E_DIM;
          int hh = e >> 6, d = e & 63;
          size_t base = ((size_t)hh * T_LEN + (PASTL + mbase)) * HDIM + d;
#pragma unroll
          for (int r = 0; r < 4; ++r) cache_v[base + (size_t)r * HDIM] = v4[r];
          ushort4 u;
          u.x = f2bf(v4[0]); u.y = f2bf(v4[1]);
          u.z = f2bf(v4[2]); u.w = f2bf(v4[3]);
          *(ushort4*)(vtb + ((size_t)hh * HDIM + d) * T_LEN + PASTL + mbase) = u;
        }
      } else {
#pragma unroll
        for (int r = 0; r < 4; ++r)
          out_f32[(size_t)(mbase + r) * E_DIM + n] = v4[r];
      }
    }
  }
}

// ---------------------------------------------------------------- attention
// KVBLK=128, ONE barrier/tile: top = vmcnt(0)+s_barrier; stage K(i+1)+V(i+1)
// (8 loads/thread) flies under the whole QK/softmax/PV of tile i.
// 4 waves/block, 32 q-rows/wave, 32x32x16 swapped QK, in-register P via
// permlane32_swap. Ks[2][128x64] + Vs[2][64x128] = 64KB (2 blk/CU).
// Grid: 896 blocks; chunks tb=c*8 128-key tiles; fid%8==head%8 affinity.
__global__ __launch_bounds__(256) void attn_kernel(
    const unsigned short* __restrict__ qb, const unsigned short* __restrict__ kb,
    const unsigned short* __restrict__ vt,
    unsigned short* __restrict__ o_part, float* __restrict__ l_part) {
  __shared__ alignas(16) unsigned short Ks[2][128 * 64];
  __shared__ alignas(16) unsigned short Vs[2][64 * 128];
  const int fid = blockIdx.x;  // 0..895
  const int h = (fid & 7) + ((fid >= 448) ? 8 : 0);
  const int g = (fid >> 3) - ((fid >= 448) ? 56 : 0);  // 0..55
  int x, c;
  if (g < 24) { x = g / 3; c = g - 3 * x; }
  else { int g2 = g - 24; x = 8 + (g2 >> 2); c = g2 & 3; }

  const int tid = threadIdx.x;
  const int w = tid >> 6;
  const int lane = tid & 63;
  const int l31 = lane & 31;
  const int hi = lane >> 5;
  const int hi4 = hi * 4;
  const int q0 = x * 128 + w * 32;

  // Q B-frags: lane (col=q=l31, hi) holds d = kk*16 + hi*8 + 0..7
  const unsigned short* qrow = qb + (size_t)(q0 + l31) * E_DIM + h * HDIM + hi * 8;
  bf16x8 qf[4];
#pragma unroll
  for (int kk = 0; kk < 4; ++kk)
    qf[kk] = *reinterpret_cast<const bf16x8*>(qrow + kk * 16);

  const unsigned short* kh = kb + (size_t)h * T_LEN * HDIM;
  const unsigned short* vh = vt + (size_t)h * HDIM * T_LEN;

  // K staging: round j (0..3): rows t0+32j+(tid>>3), seg (tid&7)^(row&7).
  const int srow = tid >> 3;  // 0..31
  const int sseg = (tid & 7) ^ (srow & 7);
  const unsigned short* ksrc = kh + (size_t)srow * HDIM + sseg * 8;
  // V staging: round j (0..3): d = 16j+(tid>>4), seg (tid&15)^(d&7).
  const int vrow = tid >> 4;  // 0..15
  const int vseg = (tid & 15) ^ (vrow & 7);
  const unsigned short* vsrc = vh + (size_t)vrow * T_LEN + vseg * 8;

  f32x16 o0, o1, zc;
#pragma unroll
  for (int i = 0; i < 16; ++i) { o0[i] = 0.f; o1[i] = 0.f; zc[i] = 0.f; }
  float lsum = 0.f;

  const int NT2full = 17 + x;            // 128-key tiles for this q-block
  const int tb = c * 8;
  const int te = (tb + 8 < NT2full) ? tb + 8 : NT2full;
  const int NT = te - tb;                // 1..8
  const int tbeg = tb * 128;
  const int qpp = q0 + l31 + PASTL;      // key > qpp => masked

  auto stageK = [&](int b, int t0) {
#pragma unroll
    for (int j = 0; j < 4; ++j)
      GLOBAL_LOAD_LDS16(ksrc + (size_t)(t0 + 32 * j) * HDIM,
                        (char*)Ks[b] + j * 4096 + tid * 16);
  };
  auto stageV = [&](int b, int t0) {
#pragma unroll
    for (int j = 0; j < 4; ++j)
      GLOBAL_LOAD_LDS16(vsrc + (size_t)(16 * j) * T_LEN + t0,
                        (char*)Vs[b] + j * 4096 + tid * 16);
  };

  stageK(0, tbeg);
  stageV(0, tbeg);
  int cur = 0;
  int t0 = tbeg;
  for (int i = 0; i < NT; ++i, t0 += 128) {
    const bool more = (i + 1 < NT);
    // ---- single sync point: K(i)+V(i) landed; buf^1 free (barrier) ----
    asm volatile("s_waitcnt vmcnt(0)" ::: "memory");
    __builtin_amdgcn_s_barrier();
    __builtin_amdgcn_sched_barrier(0);
    if (more) {
      stageK(cur ^ 1, t0 + 128);
      stageV(cur ^ 1, t0 + 128);
    }

    // ---- QK^T + softmax + P-relayout, two rb-pairs (keys 0-63, 64-127) ----
    const bool partial = (t0 + 127 > q0 + PASTL);  // wave-uniform
    const int thr = qpp - t0;
    union U4 { unsigned u[4]; bf16x8 v; };
    U4 pa[8];
#pragma unroll
    for (int half = 0; half < 2; ++half) {
      const int rbA = half * 2, rbB = half * 2 + 1;
      f32x16 sA, sB;
      __builtin_amdgcn_s_setprio(1);
      {
        int rA = rbA * 32 + l31, rB = rbB * 32 + l31;
        int slA = hi ^ (rA & 7), slB = hi ^ (rB & 7);
        bf16x8 kA = *reinterpret_cast<const bf16x8*>((const char*)Ks[cur] + rA * 128 + slA * 16);
        bf16x8 kB = *reinterpret_cast<const bf16x8*>((const char*)Ks[cur] + rB * 128 + slB * 16);
        sA = mfma32(kA, qf[0], zc);
        sB = mfma32(kB, qf[0], zc);
      }
#pragma unroll
      for (int kk = 1; kk < 4; ++kk) {
        int rA = rbA * 32 + l31, rB = rbB * 32 + l31;
        int slA = (kk * 2 + hi) ^ (rA & 7), slB = (kk * 2 + hi) ^ (rB & 7);
        bf16x8 kA = *reinterpret_cast<const bf16x8*>((const char*)Ks[cur] + rA * 128 + slA * 16);
        bf16x8 kB = *reinterpret_cast<const bf16x8*>((const char*)Ks[cur] + rB * 128 + slB * 16);
        sA = mfma32(kA, qf[kk], sA);
        sB = mfma32(kB, qf[kk], sB);
      }
      __builtin_amdgcn_s_setprio(0);

      unsigned aw[8], bw[8];
      if (!partial) {
#pragma unroll
        for (int i2 = 0; i2 < 8; ++i2) {
          float p0 = __builtin_amdgcn_exp2f(sA[2 * i2]);
          float p1 = __builtin_amdgcn_exp2f(sA[2 * i2 + 1]);
          float p2 = __builtin_amdgcn_exp2f(sB[2 * i2]);
          float p3 = __builtin_amdgcn_exp2f(sB[2 * i2 + 1]);
          lsum += (p0 + p1) + (p2 + p3);
          aw[i2] = pkbf(p0, p1);
          bw[i2] = pkbf(p2, p3);
        }
      } else {
        const int bo = half * 64;
#pragma unroll
        for (int i2 = 0; i2 < 8; ++i2) {
          int r0 = 2 * i2;
          int ko = (r0 & 3) + 8 * (r0 >> 2) + hi4 + bo;
          float p0 = __builtin_amdgcn_exp2f(sA[r0]);
          float p1 = __builtin_amdgcn_exp2f(sA[r0 + 1]);
          float p2 = __builtin_amdgcn_exp2f(sB[r0]);
          float p3 = __builtin_amdgcn_exp2f(sB[r0 + 1]);
          if (ko > thr) p0 = 0.f;
          if (ko + 1 > thr) p1 = 0.f;
          if (ko + 32 > thr) p2 = 0.f;
          if (ko + 33 > thr) p3 = 0.f;
          lsum += (p0 + p1) + (p2 + p3);
          aw[i2] = pkbf(p0, p1);
          bw[i2] = pkbf(p2, p3);
        }
      }

      {
        u32x2 r02 = __builtin_amdgcn_permlane32_swap(aw[0], aw[2], false, false);
        u32x2 r13 = __builtin_amdgcn_permlane32_swap(aw[1], aw[3], false, false);
        pa[4 * half + 0].u[0] = r02[0]; pa[4 * half + 0].u[1] = r13[0];
        pa[4 * half + 0].u[2] = r02[1]; pa[4 * half + 0].u[3] = r13[1];
        u32x2 r46 = __builtin_amdgcn_permlane32_swap(aw[4], aw[6], false, false);
        u32x2 r57 = __builtin_amdgcn_permlane32_swap(aw[5], aw[7], false, false);
        pa[4 * half + 1].u[0] = r46[0]; pa[4 * half + 1].u[1] = r57[0];
        pa[4 * half + 1].u[2] = r46[1]; pa[4 * half + 1].u[3] = r57[1];
        u32x2 s02 = __builtin_amdgcn_permlane32_swap(bw[0], bw[2], false, false);
        u32x2 s13 = __builtin_amdgcn_permlane32_swap(bw[1], bw[3], false, false);
        pa[4 * half + 2].u[0] = s02[0]; pa[4 * half + 2].u[1] = s13[0];
        pa[4 * half + 2].u[2] = s02[1]; pa[4 * half + 2].u[3] = s13[1];
        u32x2 s46 = __builtin_amdgcn_permlane32_swap(bw[4], bw[6], false, false);
        u32x2 s57 = __builtin_amdgcn_permlane32_swap(bw[5], bw[7], false, false);
        pa[4 * half + 3].u[0] = s46[0]; pa[4 * half + 3].u[1] = s57[0];
        pa[4 * half + 3].u[2] = s46[1]; pa[4 * half + 3].u[3] = s57[1];
      }
    }

    // ---- PV: 8 k-slices; V rows 256B, slot = (2ks+hi)^(d&7) ----
    __builtin_amdgcn_s_setprio(1);
#pragma unroll
    for (int ks = 0; ks < 8; ++ks) {
      int d0 = l31, d1 = 32 + l31;
      int sl0 = (2 * ks + hi) ^ (d0 & 7);
      int sl1 = (2 * ks + hi) ^ (d1 & 7);
      bf16x8 v0 = *reinterpret_cast<const bf16x8*>((const char*)Vs[cur] + d0 * 256 + sl0 * 16);
      bf16x8 v1 = *reinterpret_cast<const bf16x8*>((const char*)Vs[cur] + d1 * 256 + sl1 * 16);
      o0 = mfma32(pa[ks].v, v0, o0);
      o1 = mfma32(pa[ks].v, v1, o1);
    }
    __builtin_amdgcn_s_setprio(0);
    cur ^= 1;
  }

  lsum += __shfl_xor(lsum, 32);

  // partials: o_part[c][h][row][d] bf16, l_part[c][h][row] f32
  unsigned short* op = o_part + ((size_t)(c * NHEAD + h) * S_LEN) * HDIM;
  float* lp = l_part + (size_t)(c * NHEAD + h) * S_LEN;
  if (hi == 0) lp[q0 + l31] = lsum;
#pragma unroll
  for (int r = 0; r < 16; ++r) {
    int qr = (r & 3) + 8 * (r >> 2) + hi4;
    op[(size_t)(q0 + qr) * HDIM + l31] = f2bf(o0[r]);
    op[(size_t)(q0 + qr) * HDIM + 32 + l31] = f2bf(o1[r]);
  }
}

// Merge chunk partials (3 for rows<1024, 4 otherwise) and normalize -> ab bf16.
__global__ __launch_bounds__(256) void attn_merge_kernel(
    const unsigned short* __restrict__ o_part, const float* __restrict__ l_part,
    unsigned short* __restrict__ ab) {
  const int flat = blockIdx.x * 256 + threadIdx.x;
  const int d4 = flat & 15;
  const int row = (flat >> 4) & (S_LEN - 1);
  const int h = flat >> 15;
  const int nc = (row < 1024) ? 3 : 4;
  const size_t cstride_o = (size_t)NHEAD * S_LEN * HDIM;
  const size_t base_o = (((size_t)h * S_LEN) + row) * HDIM + d4 * 4;
  float acc[4] = {0.f, 0.f, 0.f, 0.f};
  float l = 0.f;
  for (int cc = 0; cc < nc; ++cc) {
    ushort4 u = *(const ushort4*)(o_part + cc * cstride_o + base_o);
    acc[0] += bf2f(u.x); acc[1] += bf2f(u.y);
    acc[2] += bf2f(u.z); acc[3] += bf2f(u.w);
    l += l_part[(size_t)cc * NHEAD * S_LEN + (size_t)h * S_LEN + row];
  }
  float inv = 1.f / l;
  ushort4 u;
  u.x = f2bf(acc[0] * inv);
  u.y = f2bf(acc[1] * inv);
  u.z = f2bf(acc[2] * inv);
  u.w = f2bf(acc[3] * inv);
  *(ushort4*)(ab + (size_t)row * E_DIM + h * HDIM + d4 * 4) = u;
}

// ---------------------------------------------------------------- launch

extern "C" void kernel_launch(void* const* d_in, const int* in_sizes, int n_in,
                              void* d_out, int out_size, void* d_ws, size_t ws_size,
                              hipStream_t stream) {
  (void)in_sizes; (void)n_in; (void)out_size; (void)ws_size;
  const float* x    = (const float*)d_in[0];
  const float* past = (const float*)d_in[1];
  const float* W1   = (const float*)d_in[2];
  const float* b1   = (const float*)d_in[3];
  const float* W2   = (const float*)d_in[4];
  const float* b2   = (const float*)d_in[5];

  float* out = (float*)d_out;
  float* cache_k = out + (size_t)S_LEN * E_DIM;
  float* cache_v = cache_k + (size_t)NHEAD * T_LEN * HDIM;

  // Workspace layout (42.5 MiB peak), lifetime-disjoint overlaps:
  //   [0,2)   w2t ; [2,6) qb ; [6,14) kb ; [14,22) vtb
  //   [22,26) xb -> ab ; [26,32) w1t -> o_part ; [26,42) o_part
  //   [42,42.5) l_part
  char* ws = (char*)d_ws;
  unsigned short* w2t = (unsigned short*)(ws);
  unsigned short* qb  = (unsigned short*)(ws + (size_t)(2u  << 20));
  unsigned short* kb  = (unsigned short*)(ws + (size_t)(6u  << 20));
  unsigned short* vtb = (unsigned short*)(ws + (size_t)(14u << 20));
  unsigned short* xb  = (unsigned short*)(ws + (size_t)(22u << 20));
  unsigned short* ab  = (unsigned short*)(ws + (size_t)(22u << 20));  // reuse xb
  unsigned short* w1t = (unsigned short*)(ws + (size_t)(26u << 20));
  unsigned short* o_part = (unsigned short*)(ws + (size_t)(26u << 20));  // reuse w1t
  float* l_part = (float*)(ws + (size_t)(42u << 20));

  prep_kernel<<<3584, 256, 0, stream>>>(past, x, W1, W2, cache_k, kb, xb, w1t,
                                        w2t, vtb);
  gemm_bt_kernel<0><<<768, 256, 0, stream>>>(
      xb, w1t, b1, 1024, nullptr, qb, cache_k, cache_v, kb, vtb);
  attn_kernel<<<dim3(896), 256, 0, stream>>>(qb, kb, vtb, o_part, l_part);
  attn_merge_kernel<<<(NHEAD * S_LEN * 16) / 256, 256, 0, stream>>>(o_part, l_part, ab);
  gemm_bt_kernel<1><<<256, 256, 0, stream>>>(
      ab, w2t, b2, 1024, out, nullptr, nullptr, nullptr, nullptr, nullptr);
}